// Round 3
// baseline (105.964 us; speedup 1.0000x reference)
//
#include <hip/hip_runtime.h>
#include <hip/hip_bf16.h>

#define N_ATOMS 400000
#define N_BLOCKS 50000
#define BATCHES 64
#define CCH 4
#define AX 3
#define DH 128
#define NRBF 16

// Workspace float layout
#define ACC_OFF 0          // B*17 : [cnt, zsum[12], zsq[4]] per batch
#define ZC_OFF  1088       // B*12
#define RS_OFF  1856       // B*4
#define HB_OFF  2112       // B*128
#define UID_OFF 10304      // N_ATOMS bytes (as uint8), starts at float offset 10304

typedef float f4 __attribute__((ext_vector_type(4)));

__device__ __forceinline__ f4 ntload4(const f4* p) { return __builtin_nontemporal_load(p); }
__device__ __forceinline__ void ntstore4(f4* p, f4 v) { __builtin_nontemporal_store(v, p); }
__device__ __forceinline__ float silu_f(float x) { return x / (1.f + expf(-x)); }

// ---------------- Kernel 1: per-batch stats (cnt, Zsum, Zsqsum) + uid8 ----------------
__global__ __launch_bounds__(256) void k1_stats(
    const float* __restrict__ Z, const int* __restrict__ block_id,
    const int* __restrict__ batch_id, float* __restrict__ acc,
    unsigned char* __restrict__ uid8) {
  __shared__ float bins[BATCHES * 17];
  for (int i = threadIdx.x; i < BATCHES * 17; i += 256) bins[i] = 0.f;
  __syncthreads();

  const f4* Z4 = (const f4*)Z;
  int n = blockIdx.x * 256 + threadIdx.x;
  bool valid = (n < N_ATOMS);
  int uid = -1;
  float z[12];
#pragma unroll
  for (int j = 0; j < 12; ++j) z[j] = 0.f;
  if (valid) {
    uid = batch_id[block_id[n]];
    uid8[n] = (unsigned char)uid;
    f4 a = Z4[n * 3 + 0];
    f4 b = Z4[n * 3 + 1];
    f4 c = Z4[n * 3 + 2];
    z[0] = a.x; z[1] = a.y; z[2]  = a.z; z[3]  = a.w;
    z[4] = b.x; z[5] = b.y; z[6]  = b.z; z[7]  = b.w;
    z[8] = c.x; z[9] = c.y; z[10] = c.z; z[11] = c.w;
  }

  int lo = valid ? uid : 0x7fffffff;
  int hi = uid;
#pragma unroll
  for (int m = 32; m; m >>= 1) {
    lo = min(lo, __shfl_xor(lo, m));
    hi = max(hi, __shfl_xor(hi, m));
  }

  if (lo == hi) {
    // wave-uniform uid (the common case: sorted input)
    float vals[16];
#pragma unroll
    for (int j = 0; j < 12; ++j) vals[j] = z[j];
#pragma unroll
    for (int c = 0; c < 4; ++c)
      vals[12 + c] = z[c*3]*z[c*3] + z[c*3+1]*z[c*3+1] + z[c*3+2]*z[c*3+2];
#pragma unroll
    for (int v = 0; v < 16; ++v) {
      float x = vals[v];
#pragma unroll
      for (int m = 32; m; m >>= 1) x += __shfl_xor(x, m);
      vals[v] = x;
    }
    unsigned long long mb = __ballot(valid);
    if ((threadIdx.x & 63) == 0) {
      atomicAdd(&bins[hi * 17 + 0], (float)__popcll(mb));
#pragma unroll
      for (int v = 0; v < 16; ++v) atomicAdd(&bins[hi * 17 + 1 + v], vals[v]);
    }
  } else if (hi >= 0) {
    // rare: wave straddles a batch boundary -> per-lane LDS atomics
    if (valid) {
      atomicAdd(&bins[uid * 17 + 0], 1.f);
#pragma unroll
      for (int j = 0; j < 12; ++j) atomicAdd(&bins[uid * 17 + 1 + j], z[j]);
#pragma unroll
      for (int c = 0; c < 4; ++c)
        atomicAdd(&bins[uid * 17 + 13 + c],
                  z[c*3]*z[c*3] + z[c*3+1]*z[c*3+1] + z[c*3+2]*z[c*3+2]);
    }
  }
  __syncthreads();
  for (int i = threadIdx.x; i < BATCHES * 17; i += 256) {
    float v = bins[i];
    if (v != 0.f) atomicAdd(&acc[i], v);
  }
}

// ---------------- Kernel 2: rescale + RBF + 2-layer MLP (per batch row) ----------------
__global__ __launch_bounds__(128) void k2_mlp(
    const float* __restrict__ sigma, const float* __restrict__ W1,
    const float* __restrict__ b1, const float* __restrict__ W2,
    const float* __restrict__ b2, const float* __restrict__ acc,
    float* __restrict__ Zc, float* __restrict__ resc,
    float* __restrict__ hbuf, float* __restrict__ resc_out) {
  int b = blockIdx.x, t = threadIdx.x;
  __shared__ float rbf_s[64];
  __shared__ float h1_s[128];
  __shared__ float resc_s[4];

  if (t < 4) {
    int c = t;
    float cnt = acc[b * 17];
    float cs = fmaxf(cnt, 1.f);
    float s2 = 0.f;
#pragma unroll
    for (int a = 0; a < 3; ++a) {
      float zc = acc[b * 17 + 1 + c * 3 + a] / cs;
      Zc[b * 12 + c * 3 + a] = zc;
      s2 += zc * zc;
    }
    float sq = acc[b * 17 + 13 + c] - cnt * s2;
    float denom = fmaxf(cnt * 3.f - 1.f, 1.f);
    float var = fmaxf(sq / denom, 0.f);
    float r = sigma[c] / sqrtf(var);
    resc_s[c] = r;
    resc[b * 4 + c] = r;
    resc_out[b * 4 + c] = r;
  }
  __syncthreads();
  if (t < 64) {
    int c = t >> 4, ri = t & 15;
    float ds = resc_s[c] * (1.f / 7.f);
    float env = 0.f;
    if (ds < 1.f) {
      float d2 = ds * ds;
      float d5 = d2 * d2 * ds;
      env = 1.f - 21.f * d5 + 35.f * d5 * ds - 15.f * d5 * d2;
    }
    float off = (float)ri * (1.f / 15.f);
    float dd = ds - off;
    rbf_s[t] = env * expf(-112.5f * dd * dd);
  }
  __syncthreads();
  float s = b1[t];
#pragma unroll 8
  for (int k = 0; k < 64; ++k) s += rbf_s[k] * W1[k * 128 + t];
  h1_s[t] = silu_f(s);
  __syncthreads();
  float s2 = b2[t];
#pragma unroll 8
  for (int k = 0; k < 128; ++k) s2 += h1_s[k] * W2[k * 128 + t];
  hbuf[b * 128 + t] = silu_f(s2);
}

// ---------------- Kernel 3: per-atom apply (Z out + H add + LayerNorm) ----------------
// 256 threads = 16 subgroups of 16 lanes; each subgroup handles 2 atoms
// (lane owns two f4 quarters of each 128-float row). 32 atoms per block.
__global__ __launch_bounds__(256) void k3_apply(
    const float* __restrict__ H, const float* __restrict__ Z,
    const unsigned char* __restrict__ uid8,
    const float* __restrict__ ln_w, const float* __restrict__ ln_b,
    const float* __restrict__ Zc, const float* __restrict__ resc,
    const float* __restrict__ hbuf,
    float* __restrict__ Hout, float* __restrict__ Zout) {
  int t = threadIdx.x;
  int sub = t >> 4, l = t & 15;
  int base = blockIdx.x * 32;
  int n0 = base + sub * 2;
  int n1 = n0 + 1;

  unsigned short u2 = *(const unsigned short*)&uid8[n0];
  int uid0 = u2 & 0xff, uid1 = u2 >> 8;

  const f4* H4 = (const f4*)H;
  const f4* HB4 = (const f4*)hbuf;
  size_t r0 = (size_t)n0 * 32, r1 = (size_t)n1 * 32;
  f4 v00 = ntload4(&H4[r0 + l]);
  f4 v01 = ntload4(&H4[r0 + 16 + l]);
  f4 v10 = ntload4(&H4[r1 + l]);
  f4 v11 = ntload4(&H4[r1 + 16 + l]);
  f4 hb00 = HB4[uid0 * 32 + l];
  f4 hb01 = HB4[uid0 * 32 + 16 + l];
  f4 hb10 = HB4[uid1 * 32 + l];
  f4 hb11 = HB4[uid1 * 32 + 16 + l];

  f4 x00 = v00 + hb00, x01 = v01 + hb01;
  f4 x10 = v10 + hb10, x11 = v11 + hb11;

  float s0 = (x00.x + x00.y + x00.z + x00.w) + (x01.x + x01.y + x01.z + x01.w);
  float q0 = (x00.x*x00.x + x00.y*x00.y + x00.z*x00.z + x00.w*x00.w)
           + (x01.x*x01.x + x01.y*x01.y + x01.z*x01.z + x01.w*x01.w);
  float s1 = (x10.x + x10.y + x10.z + x10.w) + (x11.x + x11.y + x11.z + x11.w);
  float q1 = (x10.x*x10.x + x10.y*x10.y + x10.z*x10.z + x10.w*x10.w)
           + (x11.x*x11.x + x11.y*x11.y + x11.z*x11.z + x11.w*x11.w);
#pragma unroll
  for (int m = 1; m < 16; m <<= 1) {
    s0 += __shfl_xor(s0, m);
    q0 += __shfl_xor(q0, m);
    s1 += __shfl_xor(s1, m);
    q1 += __shfl_xor(q1, m);
  }
  float mean0 = s0 * (1.f / 128.f);
  float inv0 = rsqrtf(q0 * (1.f / 128.f) - mean0 * mean0 + 1e-5f);
  float mean1 = s1 * (1.f / 128.f);
  float inv1 = rsqrtf(q1 * (1.f / 128.f) - mean1 * mean1 + 1e-5f);

  const f4* LW4 = (const f4*)ln_w;
  const f4* LB4 = (const f4*)ln_b;
  f4 w0 = LW4[l], w1 = LW4[16 + l];
  f4 bb0 = LB4[l], bb1 = LB4[16 + l];

  f4 o;
  f4* HO4 = (f4*)Hout;
  o.x = (x00.x - mean0) * inv0 * w0.x + bb0.x;
  o.y = (x00.y - mean0) * inv0 * w0.y + bb0.y;
  o.z = (x00.z - mean0) * inv0 * w0.z + bb0.z;
  o.w = (x00.w - mean0) * inv0 * w0.w + bb0.w;
  ntstore4(&HO4[r0 + l], o);
  o.x = (x01.x - mean0) * inv0 * w1.x + bb1.x;
  o.y = (x01.y - mean0) * inv0 * w1.y + bb1.y;
  o.z = (x01.z - mean0) * inv0 * w1.z + bb1.z;
  o.w = (x01.w - mean0) * inv0 * w1.w + bb1.w;
  ntstore4(&HO4[r0 + 16 + l], o);
  o.x = (x10.x - mean1) * inv1 * w0.x + bb0.x;
  o.y = (x10.y - mean1) * inv1 * w0.y + bb0.y;
  o.z = (x10.z - mean1) * inv1 * w0.z + bb0.z;
  o.w = (x10.w - mean1) * inv1 * w0.w + bb0.w;
  ntstore4(&HO4[r1 + l], o);
  o.x = (x11.x - mean1) * inv1 * w1.x + bb1.x;
  o.y = (x11.y - mean1) * inv1 * w1.y + bb1.y;
  o.z = (x11.z - mean1) * inv1 * w1.z + bb1.z;
  o.w = (x11.w - mean1) * inv1 * w1.w + bb1.w;
  ntstore4(&HO4[r1 + 16 + l], o);

  // Z path: threads 0..95 each handle one f4 row (atom = base + t/3, comp = t%3)
  if (t < 96) {
    int atom = base + t / 3;
    int comp = t - (t / 3) * 3;
    int uid = uid8[atom];
    const f4* Z4 = (const f4*)Z;
    f4 z = Z4[atom * 3 + comp];
    float zz[4] = {z.x, z.y, z.z, z.w};
    float oo[4];
#pragma unroll
    for (int k = 0; k < 4; ++k) {
      int j = comp * 4 + k;
      int c = j / 3;
      float zcv = Zc[uid * 12 + j];
      float r = resc[uid * 4 + c];
      oo[k] = zcv + (zz[k] - zcv) * r;
    }
    f4 ov = {oo[0], oo[1], oo[2], oo[3]};
    ntstore4(&((f4*)Zout)[atom * 3 + comp], ov);
  }
}

extern "C" void kernel_launch(void* const* d_in, const int* in_sizes, int n_in,
                              void* d_out, int out_size, void* d_ws, size_t ws_size,
                              hipStream_t stream) {
  const float* H     = (const float*)d_in[0];
  const float* Z     = (const float*)d_in[1];
  const float* sigma = (const float*)d_in[2];
  const float* W1    = (const float*)d_in[3];
  const float* b1    = (const float*)d_in[4];
  const float* W2    = (const float*)d_in[5];
  const float* b2    = (const float*)d_in[6];
  const float* ln_w  = (const float*)d_in[7];
  const float* ln_b  = (const float*)d_in[8];
  const int* block_id = (const int*)d_in[9];
  const int* batch_id = (const int*)d_in[10];

  float* ws   = (float*)d_ws;
  float* acc  = ws + ACC_OFF;
  float* Zc   = ws + ZC_OFF;
  float* resc = ws + RS_OFF;
  float* hbuf = ws + HB_OFF;
  unsigned char* uid8 = (unsigned char*)(ws + UID_OFF);

  float* Hout = (float*)d_out;
  float* Zout = Hout + (size_t)N_ATOMS * DH;
  float* resc_out = Zout + (size_t)N_ATOMS * CCH * AX;

  hipMemsetAsync(acc, 0, BATCHES * 17 * sizeof(float), stream);
  k1_stats<<<(N_ATOMS + 255) / 256, 256, 0, stream>>>(Z, block_id, batch_id, acc, uid8);
  k2_mlp<<<BATCHES, 128, 0, stream>>>(sigma, W1, b1, W2, b2, acc, Zc, resc, hbuf, resc_out);
  k3_apply<<<N_ATOMS / 32, 256, 0, stream>>>(H, Z, uid8, ln_w, ln_b,
                                             Zc, resc, hbuf, Hout, Zout);
}